// Round 8
// baseline (403.410 us; speedup 1.0000x reference)
//
#include <hip/hip_runtime.h>
#include <math.h>

// NsNet2-style fused net on MI355X (gfx950).
// Activations batch-major [B,F] fp16; layers are C[B,M] = A[B,K] @ W[M,K]^T
// via mfma_f32_16x16x32_f16 (fp32 accum). Pads: 257->320, 400->448, 600->640.
// R6: gru 53.5us @ util 30% = m97-structure ceiling (vmcnt(0) drain at every
// __syncthreads). R7 (resubmitted after acquisition timeout): (1) T4
// counted-vmcnt -- raw s_barrier + "vmcnt(5)" so the 5 in-flight stage loads
// span the barrier; lgkmcnt(0) before tail barrier keeps the
// read-before-overwrite guarantee. (2) fc GEMMs BM=256 (16 MFMA + 12 ds_read
// per step per wave vs 8+6). Swizzled LDS + XCD block swizzle kept.

#define B_TOTAL 16384
#define H16_TOTAL 3452928L   // fp16 weight elements
#define PREP_TOTAL 3460352L  // + 7424 bias floats

typedef _Float16 h8 __attribute__((ext_vector_type(8)));
typedef float f4 __attribute__((ext_vector_type(4)));

#define GLL(g, l) __builtin_amdgcn_global_load_lds(                         \
    (const __attribute__((address_space(1))) void*)(g),                     \
    (__attribute__((address_space(3))) void*)(l), 16, 0, 0)

#define MFMA(d, a_, b_) d = __builtin_amdgcn_mfma_f32_16x16x32_f16(a_, b_, d, 0, 0, 0)
#define WAITV5() asm volatile("s_waitcnt vmcnt(5)" ::: "memory")
#define WAITV0() asm volatile("s_waitcnt vmcnt(0)" ::: "memory")
#define WAITL0() asm volatile("s_waitcnt lgkmcnt(0)" ::: "memory")
#define BAR()    __builtin_amdgcn_s_barrier()

// swizzled 16B-granule index for row-major [rows][64 fp16] LDS tiles
__device__ inline int swzg(int row, int c) { return row * 8 + (c ^ (row & 7)); }

// XCD-aware swizzles (grid divisible by 8).
__device__ inline void swz_bt_mt(int bid, int& bt, int& mt) {  // 128 bt-tiles
  const int xcd = bid & 7;
  const int i = bid >> 3;
  bt = xcd * 16 + (i & 15);
  mt = i >> 4;
}
__device__ inline void swz64(int bid, int& bt, int& mt) {      // 64 bt-tiles
  const int xcd = bid & 7;
  const int i = bid >> 3;
  bt = xcd * 8 + (i & 7);
  mt = i >> 3;
}

// ---------------- weight/bias prep tables ----------------
__constant__ int kJsrc[32] = {3, 5,6,7, 8,9,10, 17,18,19, 20,21,22, 29, 31, 33,
                              4, 11,12,13, 14,15,16, 23,24,25, 26,27,28, 30, 32, 34};
__constant__ int kJM[32]   = {400, 400,400,400, 400,400,400, 400,400,400, 400,400,400, 600, 600, 257,
                              400, 400,400,400, 400,400,400, 400,400,400, 400,400,400, 600, 600, 257};
__constant__ int kJK[32]   = {257, 400,400,400, 400,400,400, 400,400,400, 400,400,400, 400, 600, 600,
                              1,1,1,1, 1,1,1, 1,1,1, 1,1,1, 1, 1, 1};
__constant__ int kJKp[32]  = {320, 448,448,448, 448,448,448, 448,448,448, 448,448,448, 448, 640, 640,
                              1,1,1,1, 1,1,1, 1,1,1, 1,1,1, 1, 1, 1};
__constant__ long kJcum[33] = {0,143360,344064,544768,745472,946176,1146880,1347584,1548288,1748992,
  1949696,2150400,2351104,2551808,2838528,3248128,3452928,3453376,3453824,3454272,3454720,3455168,
  3455616,3456064,3456512,3456960,3457408,3457856,3458304,3458752,3459392,3460032,3460352};

struct SrcPtrs { const float* p[35]; };

__global__ __launch_bounds__(256) void prep_weights(SrcPtrs sp, _Float16* __restrict__ w16,
                                                    float* __restrict__ b32) {
  long w = (long)blockIdx.x * 256 + threadIdx.x;
  if (w >= PREP_TOTAL) return;
  int j = 0;
  #pragma unroll 1
  while (j < 31 && kJcum[j + 1] <= w) j++;
  long local = w - kJcum[j];
  int Kp = kJKp[j];
  int m = (int)(local / Kp);
  int k = (int)(local - (long)m * Kp);
  float v = 0.f;
  if (m < kJM[j] && k < kJK[j]) v = sp.p[kJsrc[j]][(long)m * kJK[j] + k];
  if (j < 16) w16[w] = (_Float16)v;
  else        b32[w - H16_TOTAL] = v;
}

// ---------------- input transposes (one launch for x, h1, h2) ----------------
__global__ __launch_bounds__(256) void transpose_in(const float* __restrict__ x,
                                                    const float* __restrict__ h1,
                                                    const float* __restrict__ h2,
                                                    _Float16* __restrict__ dx,
                                                    _Float16* __restrict__ dh1,
                                                    _Float16* __restrict__ dh2) {
  __shared__ float t[32][33];
  int b = blockIdx.x;
  const float* src; _Float16* dst; int F, nFT;
  if (b < 5120)        { src = x;  dst = dx;  F = 257; nFT = 10; }
  else if (b < 12288)  { b -= 5120;  src = h1; dst = dh1; F = 400; nFT = 14; }
  else                 { b -= 12288; src = h2; dst = dh2; F = 400; nFT = 14; }
  const int Fp = nFT * 32;
  const int ft = b % nFT;
  const int bt = b / nFT;
  const int ci = threadIdx.x & 31, ri = threadIdx.x >> 5;
  #pragma unroll
  for (int p = 0; p < 4; ++p) {
    int f = ft * 32 + ri + p * 8;
    float v = (f < F) ? src[(long)f * B_TOTAL + bt * 32 + ci] : 0.f;
    t[ri + p * 8][ci] = v;
  }
  __syncthreads();
  #pragma unroll
  for (int p = 0; p < 4; ++p) {
    int bb = bt * 32 + ri + p * 8;
    dst[(long)bb * Fp + ft * 32 + ci] = (_Float16)t[ci][ri + p * 8];
  }
}

__global__ __launch_bounds__(256) void transpose_out(const float* __restrict__ src,
                                                     float* __restrict__ dst) {
  __shared__ float t[32][33];
  const int nFT = 10;
  const int ft = blockIdx.x % nFT;
  const int bt = blockIdx.x / nFT;
  const int ci = threadIdx.x & 31, ri = threadIdx.x >> 5;
  #pragma unroll
  for (int p = 0; p < 4; ++p)
    t[ri + p * 8][ci] = src[(long)(bt * 32 + ri + p * 8) * 320 + ft * 32 + ci];
  __syncthreads();
  #pragma unroll
  for (int p = 0; p < 4; ++p) {
    int f = ft * 32 + ri + p * 8;
    if (f < 257) dst[(long)f * B_TOTAL + bt * 32 + ci] = t[ci][ri + p * 8];
  }
}

// ---------------- GEMM: C[B,M] = A[B,K] @ W[M,K]^T (+bias, act) ----------------
// 256x64 tile, 512 threads (8 waves of 64x32), BK=64, dbuf, counted-vmcnt
// schedule, fully-unrolled K, swizzled LDS. ACT: 0 none, 1 relu, 2 sigmoid.
template <int ACT, int OUTF32, int K, int M>
__global__ __launch_bounds__(512, 4) void gemm_tn(const _Float16* __restrict__ A,
                                                  const _Float16* __restrict__ W,
                                                  const float* __restrict__ bias,
                                                  void* __restrict__ C) {
  constexpr int KT = K / 64;
  __shared__ __align__(16) _Float16 As2[2][256 * 64];
  __shared__ __align__(16) _Float16 Ws2[2][64 * 64];
  const int tid = threadIdx.x;
  const int l = tid & 63;
  const int w = tid >> 6;
  int bt, mt;
  swz64(blockIdx.x, bt, mt);
  const int wr = w >> 1, wc = w & 1;
  const int sc = ((l & 7) ^ (l >> 3)) * 8;  // pre-swizzled source chunk (elems)
  const int srow = tid >> 3;                // 0..63

  const _Float16* ag = A + (long)(bt * 256 + srow) * K + sc;
  const _Float16* wg = W + (long)(mt * 64 + srow) * K + sc;

  f4 acc[4][2];
  #pragma unroll
  for (int i = 0; i < 4; ++i)
    #pragma unroll
    for (int jj = 0; jj < 2; ++jj) acc[i][jj] = (f4){0.f, 0.f, 0.f, 0.f};

  const int lg = l >> 4;
  const int arow = wr * 64 + (l & 15);
  const int wrow = wc * 32 + (l & 15);

  auto stage = [&](int b, int t) {  // 5 GLL per wave (4 A + 1 W)
    #pragma unroll
    for (int j = 0; j < 4; ++j)
      GLL(ag + t * 64 + (long)j * 64 * K, (char*)As2[b] + j * 8192 + w * 1024);
    GLL(wg + t * 64, (char*)Ws2[b] + w * 1024);
  };

  stage(0, 0);
  WAITV0();
  BAR();
  #pragma unroll
  for (int i = 0; i < KT; ++i) {
    if (i + 1 < KT) { stage((i + 1) & 1, i + 1); WAITV5(); }
    else            { WAITV0(); }
    BAR();
    const h8* AsV = (const h8*)As2[i & 1];
    const h8* WsV = (const h8*)Ws2[i & 1];
    h8 b00 = WsV[swzg(wrow, lg)],      b01 = WsV[swzg(wrow, 4 | lg)];
    h8 b10 = WsV[swzg(wrow + 16, lg)], b11 = WsV[swzg(wrow + 16, 4 | lg)];
    #pragma unroll
    for (int fm = 0; fm < 4; ++fm) {
      h8 a0 = AsV[swzg(arow + fm * 16, lg)];
      h8 a1 = AsV[swzg(arow + fm * 16, 4 | lg)];
      MFMA(acc[fm][0], a0, b00); MFMA(acc[fm][0], a1, b01);
      MFMA(acc[fm][1], a0, b10); MFMA(acc[fm][1], a1, b11);
    }
    WAITL0();  // my ds_reads complete before anyone overwrites this buffer
    BAR();
  }

  const int jloc = wc * 32 + (l & 15);
  const int colBase = mt * 64 + jloc;
  if (OUTF32) {
    const int rowBase = bt * 256 + wr * 64 + (l >> 4) * 4;
    #pragma unroll
    for (int fn = 0; fn < 2; ++fn) {
      const float bb = bias[colBase + fn * 16];
      #pragma unroll
      for (int fm = 0; fm < 4; ++fm)
        #pragma unroll
        for (int r = 0; r < 4; ++r) {
          float x = acc[fm][fn][r] + bb;
          if (ACT == 2) x = 1.f / (1.f + __expf(-x));
          ((float*)C)[(long)(rowBase + fm * 16 + r) * M + colBase + fn * 16] = x;
        }
    }
  } else {
    // LDS-transpose epilogue: frags -> [256][80] fp16 (conflict-free writes)
    _Float16* scr = (_Float16*)As2;
    const int rowLoc = wr * 64 + (l >> 4) * 4;
    #pragma unroll
    for (int fn = 0; fn < 2; ++fn) {
      const float bb = bias[colBase + fn * 16];
      #pragma unroll
      for (int fm = 0; fm < 4; ++fm)
        #pragma unroll
        for (int r = 0; r < 4; ++r) {
          float x = acc[fm][fn][r] + bb;
          if (ACT == 1) x = fmaxf(x, 0.f);
          scr[(rowLoc + fm * 16 + r) * 80 + jloc + fn * 16] = (_Float16)x;
        }
    }
    __syncthreads();
    const int rq = tid & 3;
    #pragma unroll
    for (int p = 0; p < 2; ++p) {
      const int rrow = p * 128 + (tid >> 2);
      h8 v0 = *(const h8*)(scr + rrow * 80 + rq * 16);
      h8 v1 = *(const h8*)(scr + rrow * 80 + rq * 16 + 8);
      _Float16* gp = (_Float16*)C + (long)(bt * 256 + rrow) * M + mt * 64 + rq * 16;
      *(h8*)gp = v0;
      *(h8*)(gp + 8) = v1;
    }
  }
}

// ---------------- fully-fused GRU layer (4 acc groups, 8 waves) ----------------
// gates = Wi@[x] + Wh@[h], K-concat (steps 0..6 x-tiles, 7..13 h-tiles rotated
// to end at h-tile mt -> h_old in As2[1] for the blend). acc: z, r, nx, nh.
// BM=128, counted-vmcnt schedule.
__global__ __launch_bounds__(512, 4) void gemm_gru(const _Float16* __restrict__ Ax,
                                                   const _Float16* __restrict__ Ah,
                                                   const _Float16* __restrict__ Wi_,
                                                   const _Float16* __restrict__ Wh_,
                                                   const float* __restrict__ bi,
                                                   const float* __restrict__ bh,
                                                   _Float16* __restrict__ Hn) {
  __shared__ __align__(16) _Float16 As2[2][128 * 64];
  __shared__ __align__(16) _Float16 Ws2[2][3][64 * 64];
  const int tid = threadIdx.x;
  const int l = tid & 63;
  const int w = tid >> 6;
  int bt, mt;
  swz_bt_mt(blockIdx.x, bt, mt);  // mt in [0,7)
  const int wr = w >> 1, wc = w & 1;
  const int sc = ((l & 7) ^ (l >> 3)) * 8;
  const int srow = tid >> 3;

  const long arowg = (long)(bt * 128 + srow) * 448 + sc;
  const long wrowg = (long)(mt * 64 + srow) * 448 + sc;

  f4 acc[4][2][2];
  #pragma unroll
  for (int g = 0; g < 4; ++g)
    #pragma unroll
    for (int i = 0; i < 2; ++i)
      #pragma unroll
      for (int jj = 0; jj < 2; ++jj) acc[g][i][jj] = (f4){0.f, 0.f, 0.f, 0.f};

  const int lg = l >> 4;
  const int arow = wr * 32 + (l & 15);
  const int wrow = wc * 32 + (l & 15);

  // step i: i<7 -> x-tile i; i>=7 -> h-tile (mt+i-6)%7; last (i=13) = h-tile mt.
  auto stage = [&](int b, int i) {  // 5 GLL per wave (2 A + 3 W)
    const _Float16* ab = (i >= 7) ? Ah : Ax;
    const _Float16* wb = (i >= 7) ? Wh_ : Wi_;
    const int kc = ((i >= 7) ? (mt + i - 6) % 7 : i) * 64;
    GLL(ab + arowg + kc, (char*)As2[b] + w * 1024);
    GLL(ab + arowg + kc + 64 * 448, (char*)As2[b] + w * 1024 + 8192);
    #pragma unroll
    for (int g = 0; g < 3; ++g)
      GLL(wb + wrowg + (long)g * 200704 + kc, (char*)Ws2[b][g] + w * 1024);
  };

  stage(0, 0);
  WAITV0();
  BAR();
  #pragma unroll
  for (int i = 0; i < 14; ++i) {
    if (i < 13) { stage((i + 1) & 1, i + 1); WAITV5(); }
    else        { WAITV0(); }
    BAR();
    const h8* AsV = (const h8*)As2[i & 1];
    const h8* WsV = (const h8*)Ws2[i & 1][0];
    h8 a00 = AsV[swzg(arow, lg)],      a01 = AsV[swzg(arow, 4 | lg)];
    h8 a10 = AsV[swzg(arow + 16, lg)], a11 = AsV[swzg(arow + 16, 4 | lg)];
    #pragma unroll
    for (int g = 0; g < 3; ++g) {
      const int d = (g == 2) ? ((i < 7) ? 2 : 3) : g;  // folds after unroll
      h8 b00 = WsV[g * 512 + swzg(wrow, lg)];
      h8 b01 = WsV[g * 512 + swzg(wrow, 4 | lg)];
      h8 b10 = WsV[g * 512 + swzg(wrow + 16, lg)];
      h8 b11 = WsV[g * 512 + swzg(wrow + 16, 4 | lg)];
      MFMA(acc[d][0][0], a00, b00); MFMA(acc[d][0][0], a01, b01);
      MFMA(acc[d][0][1], a00, b10); MFMA(acc[d][0][1], a01, b11);
      MFMA(acc[d][1][0], a10, b00); MFMA(acc[d][1][0], a11, b01);
      MFMA(acc[d][1][1], a10, b10); MFMA(acc[d][1][1], a11, b11);
    }
    WAITL0();
    BAR();
  }

  // epilogue: gate math; h_old from As2[1] (h-tile mt); Hn via Ws2 scratch
  const _Float16* Alast = As2[1];
  _Float16* scr = (_Float16*)Ws2;  // [128][80] fp16 = 20.5 KB
  const int jloc = wc * 32 + (l & 15);
  const int rowLoc = wr * 32 + (l >> 4) * 4;
  #pragma unroll
  for (int fn = 0; fn < 2; ++fn) {
    const int j = mt * 64 + jloc + fn * 16;
    const float bz = bi[j] + bh[j];
    const float br = bi[448 + j] + bh[448 + j];
    const float bnx = bi[896 + j], bnh = bh[896 + j];
    #pragma unroll
    for (int fm = 0; fm < 2; ++fm) {
      #pragma unroll
      for (int r = 0; r < 4; ++r) {
        const float zz = 1.f / (1.f + __expf(-(acc[0][fm][fn][r] + bz)));
        const float rr = 1.f / (1.f + __expf(-(acc[1][fm][fn][r] + br)));
        const float nn = (acc[2][fm][fn][r] + bnx) + rr * (acc[3][fm][fn][r] + bnh);
        const float th = 1.f - 2.f / (__expf(2.f * nn) + 1.f);  // tanh
        const int row = rowLoc + fm * 16 + r;
        const int col = jloc + fn * 16;
        const float ho = (float)Alast[swzg(row, col >> 3) * 8 + (col & 7)];
        scr[row * 80 + col] = (_Float16)((1.f - zz) * th + zz * ho);
      }
    }
  }
  __syncthreads();
  const int rrow = tid >> 2, rq = tid & 3;
  h8 v0 = *(const h8*)(scr + rrow * 80 + rq * 16);
  h8 v1 = *(const h8*)(scr + rrow * 80 + rq * 16 + 8);
  _Float16* gp = Hn + (long)(bt * 128 + rrow) * 448 + mt * 64 + rq * 16;
  *(h8*)gp = v0;
  *(h8*)(gp + 8) = v1;
}

// ---------------- launch ----------------
extern "C" void kernel_launch(void* const* d_in, const int* in_sizes, int n_in,
                              void* d_out, int out_size, void* d_ws, size_t ws_size,
                              hipStream_t stream) {
  char* ws = (char*)d_ws;
  _Float16* W16  = (_Float16*)(ws);                 // 3,452,928 fp16
  float*    BIAS = (float*)(ws + 6905856L);         // 7,424 f32
  _Float16* buf2 = (_Float16*)(ws + 6935552L);      // xT [B,320] -> y1 [B,640] -> outT f32 [B,320]
  _Float16* buf3 = (_Float16*)(ws + 27907072L);     // fc1out [B,448] -> y2 [B,640]
  _Float16* buf4 = (_Float16*)(ws + 48878592L);     // h1_old -> h2_new [B,448]
  _Float16* buf5 = (_Float16*)(ws + 63558656L);     // h2_old [B,448]
  _Float16* buf6 = (_Float16*)(ws + 78238720L);     // h1_new [B,448]
  float* outT = (float*)buf2;                       // [B,320] f32 (y1 dead by fc4)
  if (ws_size < 92918784UL) return;  // loud failure rather than OOB

  SrcPtrs sp;
  for (int i = 0; i < 35; ++i) sp.p[i] = (const float*)d_in[i];

  prep_weights<<<dim3(13517), dim3(256), 0, stream>>>(sp, W16, BIAS);
  transpose_in<<<dim3(19456), dim3(256), 0, stream>>>((const float*)d_in[0], (const float*)d_in[1],
                                                      (const float*)d_in[2], buf2, buf4, buf5);

  // fc1: [B,320] @ [448,320]^T -> [B,448]
  gemm_tn<0, 0, 320, 448><<<dim3(64 * 7), dim3(512), 0, stream>>>(buf2, W16, BIAS, (void*)buf3);
  // GRU1 (fused): gates from [fc1out ; h1_old], writes h1_new
  gemm_gru<<<dim3(128 * 7), dim3(512), 0, stream>>>(buf3, buf4, W16 + 143360, W16 + 745472,
                                                    BIAS + 448, BIAS + 1792, buf6);
  // GRU2 (fused): gates from [h1_new ; h2_old], writes h2_new
  gemm_gru<<<dim3(128 * 7), dim3(512), 0, stream>>>(buf6, buf5, W16 + 1347584, W16 + 1949696,
                                                    BIAS + 3136, BIAS + 4480, buf4);
  // fc2 (relu), fc3 (relu), fc4 (sigmoid, fp32 out)
  gemm_tn<1, 0, 448, 640><<<dim3(64 * 10), dim3(512), 0, stream>>>(buf4, W16 + 2551808, BIAS + 5824, (void*)buf2);
  gemm_tn<1, 0, 640, 640><<<dim3(64 * 10), dim3(512), 0, stream>>>(buf2, W16 + 2838528, BIAS + 6464, (void*)buf3);
  gemm_tn<2, 1, 640, 320><<<dim3(64 * 5), dim3(512), 0, stream>>>(buf3, W16 + 3248128, BIAS + 7104, (void*)outT);

  transpose_out<<<dim3(10 * 512), dim3(256), 0, stream>>>(outT, (float*)d_out);
}

// Round 10
// 373.685 us; speedup vs baseline: 1.0795x; 1.0795x over previous
//
#include <hip/hip_runtime.h>
#include <math.h>

// NsNet2-style fused net on MI355X (gfx950).
// Activations batch-major [B,F] fp16; layers are C[B,M] = A[B,K] @ W[M,K]^T
// via mfma_f32_16x16x32_f16 (fp32 accum). Pads: 257->320, 400->448, 600->640.
// R8 post-mortem: counted-vmcnt graft = null (guide's regime gate); 9 dispatches,
// 7 non-gru average ~42us each regardless of implementation -> transition/
// overhead-bound. R9 (resubmit after acquisition timeout): fuse to 7 dispatches
// (setup = prep+3 transposes; fc4 stores d_out directly, killing transpose_out),
// setprio on gru MFMA, ws 93->76MB.

#define B_TOTAL 16384
#define H16_TOTAL 3452928L   // fp16 weight elements
#define PREP_TOTAL 3460352L  // + 7424 bias floats

typedef _Float16 h8 __attribute__((ext_vector_type(8)));
typedef float f4 __attribute__((ext_vector_type(4)));

#define GLL(g, l) __builtin_amdgcn_global_load_lds(                         \
    (const __attribute__((address_space(1))) void*)(g),                     \
    (__attribute__((address_space(3))) void*)(l), 16, 0, 0)

#define MFMA(d, a_, b_) d = __builtin_amdgcn_mfma_f32_16x16x32_f16(a_, b_, d, 0, 0, 0)
#define WAITV5() asm volatile("s_waitcnt vmcnt(5)" ::: "memory")
#define WAITV0() asm volatile("s_waitcnt vmcnt(0)" ::: "memory")
#define WAITL0() asm volatile("s_waitcnt lgkmcnt(0)" ::: "memory")
#define BAR()    __builtin_amdgcn_s_barrier()

// swizzled 16B-granule index for row-major [rows][64 fp16] LDS tiles
__device__ inline int swzg(int row, int c) { return row * 8 + (c ^ (row & 7)); }

// XCD-aware swizzles (grid divisible by 8).
__device__ inline void swz_bt_mt(int bid, int& bt, int& mt) {  // 128 bt-tiles
  const int xcd = bid & 7;
  const int i = bid >> 3;
  bt = xcd * 16 + (i & 15);
  mt = i >> 4;
}
__device__ inline void swz64(int bid, int& bt, int& mt) {      // 64 bt-tiles
  const int xcd = bid & 7;
  const int i = bid >> 3;
  bt = xcd * 8 + (i & 7);
  mt = i >> 3;
}

// ---------------- weight/bias prep tables ----------------
__constant__ int kJsrc[32] = {3, 5,6,7, 8,9,10, 17,18,19, 20,21,22, 29, 31, 33,
                              4, 11,12,13, 14,15,16, 23,24,25, 26,27,28, 30, 32, 34};
__constant__ int kJM[32]   = {400, 400,400,400, 400,400,400, 400,400,400, 400,400,400, 600, 600, 257,
                              400, 400,400,400, 400,400,400, 400,400,400, 400,400,400, 600, 600, 257};
__constant__ int kJK[32]   = {257, 400,400,400, 400,400,400, 400,400,400, 400,400,400, 400, 600, 600,
                              1,1,1,1, 1,1,1, 1,1,1, 1,1,1, 1, 1, 1};
__constant__ int kJKp[32]  = {320, 448,448,448, 448,448,448, 448,448,448, 448,448,448, 448, 640, 640,
                              1,1,1,1, 1,1,1, 1,1,1, 1,1,1, 1, 1, 1};
__constant__ long kJcum[33] = {0,143360,344064,544768,745472,946176,1146880,1347584,1548288,1748992,
  1949696,2150400,2351104,2551808,2838528,3248128,3452928,3453376,3453824,3454272,3454720,3455168,
  3455616,3456064,3456512,3456960,3457408,3457856,3458304,3458752,3459392,3460032,3460352};

struct SrcPtrs { const float* p[35]; };

// ---------------- setup: weight prep + 3 input transposes, one launch ----------
// blocks [0, 13517): prep; [13517, 13517+19456): transposes (x, h1, h2).
__global__ __launch_bounds__(256) void setup(SrcPtrs sp, _Float16* __restrict__ w16,
                                             float* __restrict__ b32,
                                             _Float16* __restrict__ dx,
                                             _Float16* __restrict__ dh1,
                                             _Float16* __restrict__ dh2) {
  __shared__ float t[32][33];
  int b = blockIdx.x;
  if (b < 13517) {
    long w = (long)b * 256 + threadIdx.x;
    if (w >= PREP_TOTAL) return;
    int j = 0;
    #pragma unroll 1
    while (j < 31 && kJcum[j + 1] <= w) j++;
    long local = w - kJcum[j];
    int Kp = kJKp[j];
    int m = (int)(local / Kp);
    int k = (int)(local - (long)m * Kp);
    float v = 0.f;
    if (m < kJM[j] && k < kJK[j]) v = sp.p[kJsrc[j]][(long)m * kJK[j] + k];
    if (j < 16) w16[w] = (_Float16)v;
    else        b32[w - H16_TOTAL] = v;
    return;
  }
  b -= 13517;
  const float* src; _Float16* dst; int F, nFT;
  if (b < 5120)        { src = sp.p[0]; dst = dx;  F = 257; nFT = 10; }
  else if (b < 12288)  { b -= 5120;  src = sp.p[1]; dst = dh1; F = 400; nFT = 14; }
  else                 { b -= 12288; src = sp.p[2]; dst = dh2; F = 400; nFT = 14; }
  const int Fp = nFT * 32;
  const int ft = b % nFT;
  const int bt = b / nFT;
  const int ci = threadIdx.x & 31, ri = threadIdx.x >> 5;
  #pragma unroll
  for (int p = 0; p < 4; ++p) {
    int f = ft * 32 + ri + p * 8;
    float v = (f < F) ? src[(long)f * B_TOTAL + bt * 32 + ci] : 0.f;
    t[ri + p * 8][ci] = v;
  }
  __syncthreads();
  #pragma unroll
  for (int p = 0; p < 4; ++p) {
    int bb = bt * 32 + ri + p * 8;
    dst[(long)bb * Fp + ft * 32 + ci] = (_Float16)t[ci][ri + p * 8];
  }
}

// ---------------- GEMM: C[B,M] = A[B,K] @ W[M,K]^T (+bias, act) ----------------
// 256x64 tile, 512 threads (8 waves of 64x32), BK=64, dbuf, counted-vmcnt
// schedule, fully-unrolled K, swizzled LDS.
// MODE 0: fp16 C via LDS-transpose epilogue (ACT 0 none / 1 relu).
// MODE 2: fc4 path -- sigmoid, store f32 DIRECTLY to out[col*16384+row]
//         (f32x4 per fragment, col<257 mask) -- transpose_out fused away.
template <int ACT, int MODE, int K, int M>
__global__ __launch_bounds__(512, 4) void gemm_tn(const _Float16* __restrict__ A,
                                                  const _Float16* __restrict__ W,
                                                  const float* __restrict__ bias,
                                                  void* __restrict__ C) {
  constexpr int KT = K / 64;
  __shared__ __align__(16) _Float16 As2[2][256 * 64];
  __shared__ __align__(16) _Float16 Ws2[2][64 * 64];
  const int tid = threadIdx.x;
  const int l = tid & 63;
  const int w = tid >> 6;
  int bt, mt;
  swz64(blockIdx.x, bt, mt);
  const int wr = w >> 1, wc = w & 1;
  const int sc = ((l & 7) ^ (l >> 3)) * 8;  // pre-swizzled source chunk (elems)
  const int srow = tid >> 3;                // 0..63

  const _Float16* ag = A + (long)(bt * 256 + srow) * K + sc;
  const _Float16* wg = W + (long)(mt * 64 + srow) * K + sc;

  f4 acc[4][2];
  #pragma unroll
  for (int i = 0; i < 4; ++i)
    #pragma unroll
    for (int jj = 0; jj < 2; ++jj) acc[i][jj] = (f4){0.f, 0.f, 0.f, 0.f};

  const int lg = l >> 4;
  const int arow = wr * 64 + (l & 15);
  const int wrow = wc * 32 + (l & 15);

  auto stage = [&](int b, int t) {  // 5 GLL per wave (4 A + 1 W)
    #pragma unroll
    for (int j = 0; j < 4; ++j)
      GLL(ag + t * 64 + (long)j * 64 * K, (char*)As2[b] + j * 8192 + w * 1024);
    GLL(wg + t * 64, (char*)Ws2[b] + w * 1024);
  };

  stage(0, 0);
  WAITV0();
  BAR();
  #pragma unroll
  for (int i = 0; i < KT; ++i) {
    if (i + 1 < KT) { stage((i + 1) & 1, i + 1); WAITV5(); }
    else            { WAITV0(); }
    BAR();
    const h8* AsV = (const h8*)As2[i & 1];
    const h8* WsV = (const h8*)Ws2[i & 1];
    h8 b00 = WsV[swzg(wrow, lg)],      b01 = WsV[swzg(wrow, 4 | lg)];
    h8 b10 = WsV[swzg(wrow + 16, lg)], b11 = WsV[swzg(wrow + 16, 4 | lg)];
    __builtin_amdgcn_s_setprio(1);
    #pragma unroll
    for (int fm = 0; fm < 4; ++fm) {
      h8 a0 = AsV[swzg(arow + fm * 16, lg)];
      h8 a1 = AsV[swzg(arow + fm * 16, 4 | lg)];
      MFMA(acc[fm][0], a0, b00); MFMA(acc[fm][0], a1, b01);
      MFMA(acc[fm][1], a0, b10); MFMA(acc[fm][1], a1, b11);
    }
    __builtin_amdgcn_s_setprio(0);
    WAITL0();  // my ds_reads complete before anyone overwrites this buffer
    BAR();
  }

  const int jloc = wc * 32 + (l & 15);
  const int colBase = mt * 64 + jloc;
  if (MODE == 2) {
    // direct transposed f32 store: out[col*16384 + row], 16B per fragment
    const int rowBase = bt * 256 + wr * 64 + (l >> 4) * 4;
    #pragma unroll
    for (int fn = 0; fn < 2; ++fn) {
      const int col = colBase + fn * 16;
      if (col < 257) {
        const float bb = bias[col];
        #pragma unroll
        for (int fm = 0; fm < 4; ++fm) {
          f4 xv;
          #pragma unroll
          for (int r = 0; r < 4; ++r)
            xv[r] = 1.f / (1.f + __expf(-(acc[fm][fn][r] + bb)));
          *(f4*)((float*)C + (long)col * B_TOTAL + rowBase + fm * 16) = xv;
        }
      }
    }
  } else {
    // LDS-transpose epilogue: frags -> [256][80] fp16 (conflict-free writes)
    _Float16* scr = (_Float16*)As2;
    const int rowLoc = wr * 64 + (l >> 4) * 4;
    #pragma unroll
    for (int fn = 0; fn < 2; ++fn) {
      const float bb = bias[colBase + fn * 16];
      #pragma unroll
      for (int fm = 0; fm < 4; ++fm)
        #pragma unroll
        for (int r = 0; r < 4; ++r) {
          float x = acc[fm][fn][r] + bb;
          if (ACT == 1) x = fmaxf(x, 0.f);
          scr[(rowLoc + fm * 16 + r) * 80 + jloc + fn * 16] = (_Float16)x;
        }
    }
    __syncthreads();
    const int rq = tid & 3;
    #pragma unroll
    for (int p = 0; p < 2; ++p) {
      const int rrow = p * 128 + (tid >> 2);
      h8 v0 = *(const h8*)(scr + rrow * 80 + rq * 16);
      h8 v1 = *(const h8*)(scr + rrow * 80 + rq * 16 + 8);
      _Float16* gp = (_Float16*)C + (long)(bt * 256 + rrow) * M + mt * 64 + rq * 16;
      *(h8*)gp = v0;
      *(h8*)(gp + 8) = v1;
    }
  }
}

// ---------------- fully-fused GRU layer (4 acc groups, 8 waves) ----------------
// gates = Wi@[x] + Wh@[h], K-concat (steps 0..6 x-tiles, 7..13 h-tiles rotated
// to end at h-tile mt -> h_old in As2[1] for the blend). acc: z, r, nx, nh.
// BM=128, counted-vmcnt schedule, setprio around MFMA cluster.
__global__ __launch_bounds__(512, 4) void gemm_gru(const _Float16* __restrict__ Ax,
                                                   const _Float16* __restrict__ Ah,
                                                   const _Float16* __restrict__ Wi_,
                                                   const _Float16* __restrict__ Wh_,
                                                   const float* __restrict__ bi,
                                                   const float* __restrict__ bh,
                                                   _Float16* __restrict__ Hn) {
  __shared__ __align__(16) _Float16 As2[2][128 * 64];
  __shared__ __align__(16) _Float16 Ws2[2][3][64 * 64];
  const int tid = threadIdx.x;
  const int l = tid & 63;
  const int w = tid >> 6;
  int bt, mt;
  swz_bt_mt(blockIdx.x, bt, mt);  // mt in [0,7)
  const int wr = w >> 1, wc = w & 1;
  const int sc = ((l & 7) ^ (l >> 3)) * 8;
  const int srow = tid >> 3;

  const long arowg = (long)(bt * 128 + srow) * 448 + sc;
  const long wrowg = (long)(mt * 64 + srow) * 448 + sc;

  f4 acc[4][2][2];
  #pragma unroll
  for (int g = 0; g < 4; ++g)
    #pragma unroll
    for (int i = 0; i < 2; ++i)
      #pragma unroll
      for (int jj = 0; jj < 2; ++jj) acc[g][i][jj] = (f4){0.f, 0.f, 0.f, 0.f};

  const int lg = l >> 4;
  const int arow = wr * 32 + (l & 15);
  const int wrow = wc * 32 + (l & 15);

  // step i: i<7 -> x-tile i; i>=7 -> h-tile (mt+i-6)%7; last (i=13) = h-tile mt.
  auto stage = [&](int b, int i) {  // 5 GLL per wave (2 A + 3 W)
    const _Float16* ab = (i >= 7) ? Ah : Ax;
    const _Float16* wb = (i >= 7) ? Wh_ : Wi_;
    const int kc = ((i >= 7) ? (mt + i - 6) % 7 : i) * 64;
    GLL(ab + arowg + kc, (char*)As2[b] + w * 1024);
    GLL(ab + arowg + kc + 64 * 448, (char*)As2[b] + w * 1024 + 8192);
    #pragma unroll
    for (int g = 0; g < 3; ++g)
      GLL(wb + wrowg + (long)g * 200704 + kc, (char*)Ws2[b][g] + w * 1024);
  };

  stage(0, 0);
  WAITV0();
  BAR();
  #pragma unroll
  for (int i = 0; i < 14; ++i) {
    if (i < 13) { stage((i + 1) & 1, i + 1); WAITV5(); }
    else        { WAITV0(); }
    BAR();
    const h8* AsV = (const h8*)As2[i & 1];
    const h8* WsV = (const h8*)Ws2[i & 1][0];
    h8 a00 = AsV[swzg(arow, lg)],      a01 = AsV[swzg(arow, 4 | lg)];
    h8 a10 = AsV[swzg(arow + 16, lg)], a11 = AsV[swzg(arow + 16, 4 | lg)];
    __builtin_amdgcn_s_setprio(1);
    #pragma unroll
    for (int g = 0; g < 3; ++g) {
      const int d = (g == 2) ? ((i < 7) ? 2 : 3) : g;  // folds after unroll
      h8 b00 = WsV[g * 512 + swzg(wrow, lg)];
      h8 b01 = WsV[g * 512 + swzg(wrow, 4 | lg)];
      h8 b10 = WsV[g * 512 + swzg(wrow + 16, lg)];
      h8 b11 = WsV[g * 512 + swzg(wrow + 16, 4 | lg)];
      MFMA(acc[d][0][0], a00, b00); MFMA(acc[d][0][0], a01, b01);
      MFMA(acc[d][0][1], a00, b10); MFMA(acc[d][0][1], a01, b11);
      MFMA(acc[d][1][0], a10, b00); MFMA(acc[d][1][0], a11, b01);
      MFMA(acc[d][1][1], a10, b10); MFMA(acc[d][1][1], a11, b11);
    }
    __builtin_amdgcn_s_setprio(0);
    WAITL0();
    BAR();
  }

  // epilogue: gate math; h_old from As2[1] (h-tile mt); Hn via Ws2 scratch
  const _Float16* Alast = As2[1];
  _Float16* scr = (_Float16*)Ws2;  // [128][80] fp16 = 20.5 KB
  const int jloc = wc * 32 + (l & 15);
  const int rowLoc = wr * 32 + (l >> 4) * 4;
  #pragma unroll
  for (int fn = 0; fn < 2; ++fn) {
    const int j = mt * 64 + jloc + fn * 16;
    const float bz = bi[j] + bh[j];
    const float br = bi[448 + j] + bh[448 + j];
    const float bnx = bi[896 + j], bnh = bh[896 + j];
    #pragma unroll
    for (int fm = 0; fm < 2; ++fm) {
      #pragma unroll
      for (int r = 0; r < 4; ++r) {
        const float zz = 1.f / (1.f + __expf(-(acc[0][fm][fn][r] + bz)));
        const float rr = 1.f / (1.f + __expf(-(acc[1][fm][fn][r] + br)));
        const float nn = (acc[2][fm][fn][r] + bnx) + rr * (acc[3][fm][fn][r] + bnh);
        const float th = 1.f - 2.f / (__expf(2.f * nn) + 1.f);  // tanh
        const int row = rowLoc + fm * 16 + r;
        const int col = jloc + fn * 16;
        const float ho = (float)Alast[swzg(row, col >> 3) * 8 + (col & 7)];
        scr[row * 80 + col] = (_Float16)((1.f - zz) * th + zz * ho);
      }
    }
  }
  __syncthreads();
  const int rrow = tid >> 2, rq = tid & 3;
  h8 v0 = *(const h8*)(scr + rrow * 80 + rq * 16);
  h8 v1 = *(const h8*)(scr + rrow * 80 + rq * 16 + 8);
  _Float16* gp = Hn + (long)(bt * 128 + rrow) * 448 + mt * 64 + rq * 16;
  *(h8*)gp = v0;
  *(h8*)(gp + 8) = v1;
}

// ---------------- launch ----------------
extern "C" void kernel_launch(void* const* d_in, const int* in_sizes, int n_in,
                              void* d_out, int out_size, void* d_ws, size_t ws_size,
                              hipStream_t stream) {
  char* ws = (char*)d_ws;
  // compacted layout (76.1 MB) with verified-dead aliasing:
  _Float16* W16   = (_Float16*)(ws);                // 6,905,856 B
  float*    BIAS  = (float*)(ws + 6905856L);        // 29,696 B
  _Float16* xT    = (_Float16*)(ws + 6935552L);     // [B,320] 10.5 MB
  _Float16* fc1o  = (_Float16*)(ws + 17421312L);    // [B,448] 14.7 MB
  _Float16* h1old = (_Float16*)(ws + 32101376L);    // [B,448]; later h2new
  _Float16* h2old = (_Float16*)(ws + 46781440L);    // [B,448]
  _Float16* h1new = (_Float16*)(ws + 61461504L);    // [B,448]
  _Float16* y1    = xT;                             // [B,640] 21 MB over xT+fc1o (dead)
  _Float16* y2    = h2old;                          // [B,640] 21 MB over h2old+h1new (dead)
  _Float16* h2new = h1old;                          // h1old dead after gru1
  if (ws_size < 76141568UL) return;  // loud failure rather than OOB

  SrcPtrs sp;
  for (int i = 0; i < 35; ++i) sp.p[i] = (const float*)d_in[i];

  // setup: weight/bias prep (13517 blocks) + x/h1/h2 transposes (19456 blocks)
  setup<<<dim3(32973), dim3(256), 0, stream>>>(sp, W16, BIAS, xT, h1old, h2old);

  // fc1: [B,320] @ [448,320]^T -> [B,448]
  gemm_tn<0, 0, 320, 448><<<dim3(64 * 7), dim3(512), 0, stream>>>(xT, W16, BIAS, (void*)fc1o);
  // GRU1 (fused): gates from [fc1out ; h1_old], writes h1_new
  gemm_gru<<<dim3(128 * 7), dim3(512), 0, stream>>>(fc1o, h1old, W16 + 143360, W16 + 745472,
                                                    BIAS + 448, BIAS + 1792, h1new);
  // GRU2 (fused): gates from [h1_new ; h2_old], writes h2_new (over h1old slot)
  gemm_gru<<<dim3(128 * 7), dim3(512), 0, stream>>>(h1new, h2old, W16 + 1347584, W16 + 1949696,
                                                    BIAS + 3136, BIAS + 4480, h2new);
  // fc2 (relu) -> y1, fc3 (relu) -> y2, fc4 (sigmoid) -> d_out directly
  gemm_tn<1, 0, 448, 640><<<dim3(64 * 10), dim3(512), 0, stream>>>(h2new, W16 + 2551808, BIAS + 5824, (void*)y1);
  gemm_tn<1, 0, 640, 640><<<dim3(64 * 10), dim3(512), 0, stream>>>(y1, W16 + 2838528, BIAS + 6464, (void*)y2);
  gemm_tn<2, 2, 640, 320><<<dim3(64 * 5), dim3(512), 0, stream>>>(y2, W16 + 3248128, BIAS + 7104, d_out);
}